// Round 8
// baseline (145.020 us; speedup 1.0000x reference)
//
#include <hip/hip_runtime.h>

#define N_FEATS 256
#define HIDDEN  128
#define N_CLASS 64
#define BATCH   1024
#define K0      25
#define K1      10
#define N_HIST  5
#define M_TOTAL (BATCH + BATCH * K1)   // 11264 layer-0 rows
#define KDIM    512
#define N_NODES 100000

typedef unsigned short u16;
typedef short bf16x8 __attribute__((ext_vector_type(8)));
typedef _Float16 f16x8 __attribute__((ext_vector_type(8)));
typedef float f32x4 __attribute__((ext_vector_type(4)));

static __device__ __forceinline__ u16 f2bf(float f) {
    union { float f; unsigned int i; } v;
    v.f = f;
    unsigned int x = v.i;
    x += ((x >> 16) & 1u) + 0x7FFFu;   // round-to-nearest-even
    return (u16)(x >> 16);
}
static __device__ __forceinline__ unsigned int pack2(float lo, float hi) {
    return (unsigned int)f2bf(lo) | ((unsigned int)f2bf(hi) << 16);
}
static __device__ __forceinline__ u16 f2h(float f) {
    union { _Float16 h; u16 u; } v;
    v.h = (_Float16)f;                 // v_cvt_f16_f32, RTE
    return v.u;
}
// Dual-width int load: little-endian low word == value for both int32/int64.
static __device__ __forceinline__ int loadI(const void* p, long long i, int f64) {
    const char* cp = (const char*)p + (f64 ? (i << 3) : (i << 2));
    return *(const int*)cp;
}

// ---------------------------------------------------------------------------
// int64-vs-int32 detection (odd int32 slots of nodes all zero => int64).
// ---------------------------------------------------------------------------
__global__ void k_detect(const void* __restrict__ nodes, int* __restrict__ flag) {
    if (threadIdx.x == 0 && blockIdx.x == 0) {
        const int* p = (const int*)nodes;
        int f = 1;
        for (int i = 0; i < 8; ++i)
            if (p[2 * i + 1] != 0) f = 0;
        *flag = f;
    }
}

// ===========================================================================
// PROJECTION PATH: P = feats @ [W0_top | W0_bot]  (100000 x 256, fp16), then
// layer-0 rows become pure gathers of 256B P-slices instead of 26KB of feats.
// ===========================================================================

// W0 fp32 (512x128) -> fp16 W0T2 (256x256). Folds int64 detection.
__global__ void k_transpose_w0h(const float* __restrict__ W0, u16* __restrict__ W0T2,
                                const void* __restrict__ nodes, int* __restrict__ flag) {
    if (threadIdx.x == 0 && threadIdx.y == 0 && blockIdx.x == 0 && blockIdx.y == 0) {
        const int* p = (const int*)nodes;
        int f = 1;
        for (int i = 0; i < 8; ++i)
            if (p[2 * i + 1] != 0) f = 0;
        *flag = f;
    }
    __shared__ u16 tile[32][33];
    int tx = threadIdx.x;            // 0..31
    int ty = threadIdx.y;            // 0..7
    int k0 = blockIdx.x * 32;        // over K=512 (16 blocks)
    int n0 = blockIdx.y * 32;        // over N=128 (4 blocks)
#pragma unroll
    for (int i = 0; i < 32; i += 8)
        tile[ty + i][tx] = f2h(W0[(size_t)(k0 + ty + i) * HIDDEN + n0 + tx]);
    __syncthreads();
    int roff = (k0 >= 256) ? 128 : 0;
    int kk = k0 & 255;
#pragma unroll
    for (int i = 0; i < 32; i += 8)
        W0T2[(size_t)(n0 + ty + i + roff) * 256 + kk + tx] = tile[tx][ty + i];
}

// Projection GEMM v8 -- NO LDS, NO BARRIERS, CONTINUOUS LOAD ISSUE.
// Post-mortem of R1-R7 (seven schedules, all ~48-50us, ~2-3 TB/s): every
// variant staged A through LDS with per-epoch all-wave rendezvous and issued
// each wave's loads in one burst per epoch -> memory-pipe duty cycle ~20%.
// Here A-fragments are loaded DIRECTLY from global in the MFMA lane layout
// (lane(m,q) reads feats[row][kk*32+q*8], two float4 = 128B-aligned segments),
// double-buffered in registers at kk-pair granularity: a 4-step rotation
// issues 4 loads every ~100cy, 8 in flight per wave at all times, counted
// vmcnt waits derived from register reuse. B register-resident; acc stored
// directly to P. 512 blocks (2/CU at VGPR<=128) x 8 fully independent waves;
// the 8 col-waves of a block share each 16KB row-stripe via L1/L2 (block's
// chunk << 4MB L2), so the 8x A re-read stays on-chip.
#define NT16     (N_NODES / 16)      // 6250 16-row stripes exactly
#define P8_NBLK  512
__global__ __launch_bounds__(512, 4) void k_proj8(
        const float* __restrict__ feats,
        const u16* __restrict__ W0T2,
        u16* __restrict__ P) {
    const int tid = threadIdx.x;
    const int wv = tid >> 6;
    const int lane = tid & 63;
    const int m = lane & 15;
    const int q = lane >> 4;
    const int bi = blockIdx.x;
    const int base = NT16 / P8_NBLK;           // 12
    const int rem  = NT16 - base * P8_NBLK;    // 106
    const int s0 = bi * base + (bi < rem ? bi : rem);
    const int cnt = base + (bi < rem ? 1 : 0); // 12 or 13 (>= 2)

    // Loop-invariant B fragments (W0T2 rows = output cols, K contiguous).
    f16x8 B0[8], B1[8];
    {
        const u16* bb = W0T2 + (size_t)(wv * 32 + m) * 256 + q * 8;
#pragma unroll
        for (int kk = 0; kk < 8; ++kk) {
            B0[kk] = *(const f16x8*)(bb + kk * 32);
            B1[kk] = *(const f16x8*)(bb + 16 * 256 + kk * 32);
        }
    }

    // Per-lane A base: row = t*16 + m, col = q*8. Pair p covers kk=2p,2p+1.
    const float* abase = feats + (size_t)m * N_FEATS + q * 8;
    float4 sA0, sA1, sA2, sA3, sB0, sB1, sB2, sB3;

#define P8_ISSUE(S0, S1, S2, S3, t, p)                                        \
    {                                                                         \
        const float* ap_ = abase + (size_t)(t) * (16 * N_FEATS) + (p) * 64;   \
        S0 = *(const float4*)(ap_);                                           \
        S1 = *(const float4*)(ap_ + 4);                                       \
        S2 = *(const float4*)(ap_ + 32);                                      \
        S3 = *(const float4*)(ap_ + 36);                                      \
    }
#define P8_COMP(S0, S1, S2, S3, k0v)                                          \
    {                                                                         \
        f16x8 af0, af1;                                                       \
        af0[0] = (_Float16)S0.x; af0[1] = (_Float16)S0.y;                     \
        af0[2] = (_Float16)S0.z; af0[3] = (_Float16)S0.w;                     \
        af0[4] = (_Float16)S1.x; af0[5] = (_Float16)S1.y;                     \
        af0[6] = (_Float16)S1.z; af0[7] = (_Float16)S1.w;                     \
        af1[0] = (_Float16)S2.x; af1[1] = (_Float16)S2.y;                     \
        af1[2] = (_Float16)S2.z; af1[3] = (_Float16)S2.w;                     \
        af1[4] = (_Float16)S3.x; af1[5] = (_Float16)S3.y;                     \
        af1[6] = (_Float16)S3.z; af1[7] = (_Float16)S3.w;                     \
        a0 = __builtin_amdgcn_mfma_f32_16x16x32_f16(af0, B0[k0v], a0, 0, 0, 0);     \
        a1 = __builtin_amdgcn_mfma_f32_16x16x32_f16(af0, B1[k0v], a1, 0, 0, 0);     \
        a0 = __builtin_amdgcn_mfma_f32_16x16x32_f16(af1, B0[(k0v) + 1], a0, 0, 0, 0); \
        a1 = __builtin_amdgcn_mfma_f32_16x16x32_f16(af1, B1[(k0v) + 1], a1, 0, 0, 0); \
    }

    P8_ISSUE(sA0, sA1, sA2, sA3, s0, 0);       // kk 0,1 of first stripe
    P8_ISSUE(sB0, sB1, sB2, sB3, s0, 1);       // kk 2,3

    for (int tt = 0; tt < cnt; ++tt) {
        const int t = s0 + tt;
        f32x4 a0 = (f32x4){0.f, 0.f, 0.f, 0.f};
        f32x4 a1 = (f32x4){0.f, 0.f, 0.f, 0.f};

        P8_COMP(sA0, sA1, sA2, sA3, 0);              // consume kk0,1
        P8_ISSUE(sA0, sA1, sA2, sA3, t, 2);          // issue kk4,5
        P8_COMP(sB0, sB1, sB2, sB3, 2);              // consume kk2,3
        P8_ISSUE(sB0, sB1, sB2, sB3, t, 3);          // issue kk6,7
        P8_COMP(sA0, sA1, sA2, sA3, 4);              // consume kk4,5
        if (tt + 1 < cnt) P8_ISSUE(sA0, sA1, sA2, sA3, t + 1, 0);
        P8_COMP(sB0, sB1, sB2, sB3, 6);              // consume kk6,7
        if (tt + 1 < cnt) P8_ISSUE(sB0, sB1, sB2, sB3, t + 1, 1);

        // D: row=q*4+r, col=lane&15. 16-lane groups store 32B-contiguous runs.
        u16* prow = P + (size_t)(t * 16 + q * 4) * 256 + wv * 32 + m;
#pragma unroll
        for (int r = 0; r < 4; ++r) {
            prow[(size_t)r * 256]      = f2h(a0[r]);
            prow[(size_t)r * 256 + 16] = f2h(a1[r]);
        }
    }
#undef P8_ISSUE
#undef P8_COMP
}

// Fused gather + layer-1 (R3-proven, best measured): one 256-thread block
// (4 waves) per batch row b.
__global__ __launch_bounds__(256) void k_gf(
        const u16* __restrict__ P,
        const float* __restrict__ history,
        const void* __restrict__ nodes,
        const void* __restrict__ neighs0,
        const void* __restrict__ neighs1,
        const void* __restrict__ neighs0_nb,
        const void* __restrict__ h_nodes,
        const float* __restrict__ b0,
        const float* __restrict__ W1,
        const float* __restrict__ b1,
        float* __restrict__ out,
        const int* __restrict__ flag) {
    __shared__ float Hs[11][128];
    __shared__ float hcat[2 * HIDDEN];
    __shared__ float red[256];
    const int f64 = *flag;
    const int tid = threadIdx.x;
    const int b = blockIdx.x;
    const int wv = tid >> 6;
    const int lane = tid & 63;
    const int m = lane & 15;
    const int grp = lane >> 4;

    // ---- Stage A: rows wv, wv+4, wv+8 (<11)
    for (int r = wv; r < 11; r += 4) {
        int selfIdx;
        const void* nbp;
        long long nbo;
        if (r == 0) {
            selfIdx = loadI(nodes, b, f64);
            nbp = neighs0; nbo = (long long)b * K0;
        } else {
            int rr = b * K1 + (r - 1);
            selfIdx = loadI(neighs1, rr, f64);
            nbp = neighs0_nb; nbo = (long long)rr * K0;
        }
        int idx[K0];
#pragma unroll
        for (int k = 0; k < K0; ++k) idx[k] = loadI(nbp, nbo + k, f64);

        float a[8];
#pragma unroll
        for (int i = 0; i < 8; ++i) a[i] = 0.f;
#pragma unroll
        for (int k = 0; k < 7; ++k) {
            int k1 = 4 * k + grp;
            if (k1 < K0) {
                f16x8 v = *(const f16x8*)(P + (size_t)idx[k1] * 256 + 128 + m * 8);
#pragma unroll
                for (int i = 0; i < 8; ++i) a[i] += (float)v[i];
            }
        }
#pragma unroll
        for (int i = 0; i < 8; ++i) {
            a[i] += __shfl_xor(a[i], 16);
            a[i] += __shfl_xor(a[i], 32);
        }
        if (grp == 0) {
            f16x8 sv = *(const f16x8*)(P + (size_t)selfIdx * 256 + m * 8);
            const float inv = 1.0f / (float)K0;
#pragma unroll
            for (int i = 0; i < 8; ++i) {
                float y = a[i] * inv + (float)sv[i] + b0[m * 8 + i];
                Hs[r][m * 8 + i] = y > 0.f ? y : 0.f;
            }
        }
    }
    __syncthreads();

    // ---- Stage B: half 0 does t=0..4 (+h1), half 1 does t=5..9 (+history).
    const int j = tid & 127;
    const int half = tid >> 7;
    float S = 0.f;
    if (half == 0) hcat[j] = Hs[0][j];
#pragma unroll
    for (int t = half * 5; t < half * 5 + 5; ++t) {
        int n1 = loadI(neighs1, b * K1 + t, f64);
        S += 0.5f * (Hs[1 + t][j] - history[(size_t)n1 * HIDDEN + j]);
    }
    if (half == 1) {
#pragma unroll
        for (int u = 0; u < N_HIST; ++u) {
            int hn = loadI(h_nodes, b * N_HIST + u, f64);
            S += history[(size_t)hn * HIDDEN + j];
        }
    }
    red[tid] = S;
    __syncthreads();
    if (half == 0)
        hcat[HIDDEN + j] = (red[j] + red[HIDDEN + j]) * (1.0f / 15.0f);
    __syncthreads();

    // ---- Stage C: 4 threads per class column, 64-length partial dots.
    const int n = tid & 63;
    const int seg = tid >> 6;
    float p = 0.f;
#pragma unroll 8
    for (int i = seg * 64; i < seg * 64 + 64; ++i)
        p += hcat[i] * W1[(size_t)i * N_CLASS + n];
    red[tid] = p;
    __syncthreads();
    if (tid < 64) {
        float a = red[tid] + red[tid + 64] + red[tid + 128] + red[tid + 192]
                + b1[tid];
        a = a > 0.f ? a : 0.f;
        out[(size_t)b * N_CLASS + tid] = a;
    }
}

// ===========================================================================
// MIDDLE TIER (proven 65.5us path): kept verbatim for ws too small for P.
// ===========================================================================
__global__ void k_transpose_w0(const float* __restrict__ W0, u16* __restrict__ W0T) {
    __shared__ u16 tile[32][33];
    int tx = threadIdx.x;
    int ty = threadIdx.y;
    int k0 = blockIdx.x * 32;
    int n0 = blockIdx.y * 32;
#pragma unroll
    for (int i = 0; i < 32; i += 8)
        tile[ty + i][tx] = f2bf(W0[(size_t)(k0 + ty + i) * HIDDEN + n0 + tx]);
    __syncthreads();
#pragma unroll
    for (int i = 0; i < 32; i += 8)
        W0T[(size_t)(n0 + ty + i) * KDIM + k0 + tx] = tile[tx][ty + i];
}

__global__ __launch_bounds__(512) void k_layer0(
        const float* __restrict__ feats,
        const void* __restrict__ nodes,
        const void* __restrict__ neighs0,
        const void* __restrict__ neighs1,
        const void* __restrict__ neighs0_nb,
        const u16* __restrict__ W0T,
        const float* __restrict__ b0,
        float* __restrict__ H,
        const int* __restrict__ flag) {
    __shared__ u16 Xs[16][KDIM + 8];
    const int f64 = *flag;
    int wv = threadIdx.x >> 6;
    int lane = threadIdx.x & 63;
    int row0 = blockIdx.x * 16;
    int d = lane * 4;

#pragma unroll
    for (int i = 0; i < 2; ++i) {
        int lr = wv * 2 + i;
        int g = row0 + lr;
        int selfIdx;
        const void* nbp;
        long long nbo;
        if (g < BATCH) {
            selfIdx = loadI(nodes, g, f64);
            nbp = neighs0; nbo = (long long)g * K0;
        } else {
            int rr = g - BATCH;
            selfIdx = loadI(neighs1, rr, f64);
            nbp = neighs0_nb; nbo = (long long)rr * K0;
        }
        int idx[K0];
#pragma unroll
        for (int k = 0; k < K0; ++k) idx[k] = loadI(nbp, nbo + k, f64);

        float4 sv = *(const float4*)(feats + (size_t)selfIdx * N_FEATS + d);
        float a0 = 0.f, a1 = 0.f, a2 = 0.f, a3 = 0.f;
#pragma unroll
        for (int k = 0; k < K0; ++k) {
            float4 v = *(const float4*)(feats + (size_t)idx[k] * N_FEATS + d);
            a0 += v.x; a1 += v.y; a2 += v.z; a3 += v.w;
        }
        const float inv = 1.0f / (float)K0;
        uint2 spk, mpk;
        spk.x = pack2(sv.x, sv.y);
        spk.y = pack2(sv.z, sv.w);
        mpk.x = pack2(a0 * inv, a1 * inv);
        mpk.y = pack2(a2 * inv, a3 * inv);
        *(uint2*)&Xs[lr][d] = spk;
        *(uint2*)&Xs[lr][N_FEATS + d] = mpk;
    }
    __syncthreads();

    int m = lane & 15;
    int q = lane >> 4;
    f32x4 acc = (f32x4){0.f, 0.f, 0.f, 0.f};
    const u16* bbase = W0T + (size_t)(wv * 16 + m) * KDIM + q * 8;
#pragma unroll
    for (int k0 = 0; k0 < KDIM; k0 += 32) {
        bf16x8 af = *(const bf16x8*)&Xs[m][k0 + q * 8];
        bf16x8 bf = *(const bf16x8*)(bbase + k0);
        acc = __builtin_amdgcn_mfma_f32_16x16x32_bf16(af, bf, acc, 0, 0, 0);
    }
    int col = wv * 16 + m;
    float bias = b0[col];
#pragma unroll
    for (int r = 0; r < 4; ++r) {
        float y = acc[r] + bias;
        y = y > 0.f ? y : 0.f;
        H[(size_t)(row0 + q * 4 + r) * HIDDEN + col] = y;
    }
}

__global__ __launch_bounds__(256) void k_final(
        const float* __restrict__ H,
        const float* __restrict__ history,
        const void* __restrict__ neighs1,
        const void* __restrict__ h_nodes,
        const float* __restrict__ W1,
        const float* __restrict__ b1,
        float* __restrict__ out,
        const int* __restrict__ flag) {
    __shared__ float hcat[2 * HIDDEN];
    __shared__ float red[256];
    const int f64 = *flag;
    const int tid = threadIdx.x;
    const int b = blockIdx.x;
    const int j = tid & 127;
    const int half = tid >> 7;

    float S = 0.f;
    if (half == 0) hcat[j] = H[(size_t)b * HIDDEN + j];
#pragma unroll
    for (int t = half * 5; t < half * 5 + 5; ++t) {
        float orig = H[(size_t)(BATCH + b * K1 + t) * HIDDEN + j];
        int n1 = loadI(neighs1, b * K1 + t, f64);
        float hist = history[(size_t)n1 * HIDDEN + j];
        S += 0.5f * (orig - hist);
    }
    if (half == 1) {
#pragma unroll
        for (int u = 0; u < N_HIST; ++u) {
            int hn = loadI(h_nodes, b * N_HIST + u, f64);
            S += history[(size_t)hn * HIDDEN + j];
        }
    }
    red[tid] = S;
    __syncthreads();
    if (half == 0)
        hcat[HIDDEN + j] = (red[j] + red[HIDDEN + j]) * (1.0f / 15.0f);
    __syncthreads();

    const int n = tid & 63;
    const int seg = tid >> 6;
    float p = 0.f;
#pragma unroll 8
    for (int i = seg * 64; i < seg * 64 + 64; ++i)
        p += hcat[i] * W1[(size_t)i * N_CLASS + n];
    red[tid] = p;
    __syncthreads();
    if (tid < 64) {
        float a = red[tid] + red[tid + 64] + red[tid + 128] + red[tid + 192]
                + b1[tid];
        a = a > 0.f ? a : 0.f;
        out[(size_t)b * N_CLASS + tid] = a;
    }
}

// ===========================================================================
// Fallback: known-good monolithic kernel (used only if ws too small).
// ===========================================================================
static __device__ __forceinline__ float loadF_m(const void* p, long long i, int fbf) {
    const char* cp = (const char*)p + (fbf ? (i << 1) : (i << 2));
    if (fbf) {
        union { unsigned int u; float f; } v;
        v.u = ((unsigned int)(*(const u16*)cp)) << 16;
        return v.f;
    }
    return *(const float*)cp;
}

__global__ __launch_bounds__(256) void k_fused(
        const void* __restrict__ feats,
        const void* __restrict__ history,
        const void* __restrict__ W0,
        const void* __restrict__ b0,
        const void* __restrict__ W1,
        const void* __restrict__ b1,
        const void* __restrict__ nodes,
        const void* __restrict__ neighs0,
        const void* __restrict__ neighs1,
        const void* __restrict__ neighs0_nb,
        const void* __restrict__ h_nodes,
        float* __restrict__ out) {
    __shared__ float W0s[32][128];
    __shared__ float Xs[11][KDIM];
    __shared__ float hcat[2 * HIDDEN];
    __shared__ float red[256];
    __shared__ int ibuf[K0 + 1];
    __shared__ int sflags[2];

    const int tid = threadIdx.x;
    const int b = blockIdx.x;

    if (tid == 0) {
        const int* ip = (const int*)nodes;
        int f = 1;
        for (int i = 0; i < 8; ++i)
            if (ip[2 * i + 1] != 0) f = 0;
        sflags[0] = f;
        const u16* qp = (const u16*)feats;
        int cnt = 0;
        for (int i = 0; i < 64; ++i) {
            int e = (qp[2 * i] >> 7) & 0xFF;
            if (e >= 90 && e <= 134) cnt++;
        }
        sflags[1] = (cnt >= 40) ? 1 : 0;
    }
    __syncthreads();
    const int f64 = sflags[0];
    const int fbf = sflags[1];

    for (int r = 0; r < 11; ++r) {
        __syncthreads();
        if (tid < K0) {
            long long nbo = (r == 0) ? ((long long)b * K0)
                                     : ((long long)(b * K1 + (r - 1)) * K0);
            const void* nbp = (r == 0) ? neighs0 : neighs0_nb;
            ibuf[tid] = loadI(nbp, nbo + tid, f64);
        } else if (tid == K0) {
            ibuf[K0] = (r == 0) ? loadI(nodes, b, f64)
                                : loadI(neighs1, b * K1 + (r - 1), f64);
        }
        __syncthreads();
        int sidx = ibuf[K0];
        Xs[r][tid] = loadF_m(feats, (long long)sidx * N_FEATS + tid, fbf);
        float s = 0.f;
#pragma unroll
        for (int k = 0; k < K0; ++k)
            s += loadF_m(feats, (long long)ibuf[k] * N_FEATS + tid, fbf);
        Xs[r][N_FEATS + tid] = s * (1.0f / (float)K0);
    }
    __syncthreads();

    const int c = tid & 127;
    const int ph = tid >> 7;
    float acc[11];
#pragma unroll
    for (int r = 0; r < 11; ++r) acc[r] = 0.f;

    for (int s = 0; s < 16; ++s) {
        __syncthreads();
#pragma unroll
        for (int i = 0; i < 16; ++i) {
            int idx = tid + 256 * i;
            int k = idx >> 7, cc = idx & 127;
            W0s[k][cc] = loadF_m(W0, (long long)(32 * s + k) * HIDDEN + cc, fbf);
        }
        __syncthreads();
        const int kb = 32 * s + 16 * ph;
#pragma unroll
        for (int r = 0; r < 11; ++r) {
            float a = 0.f;
#pragma unroll
            for (int j = 0; j < 16; ++j)
                a += Xs[r][kb + j] * W0s[16 * ph + j][c];
            acc[r] += a;
        }
    }

    float S = 0.f;
    float b0v = (tid < 128) ? loadF_m(b0, tid, fbf) : 0.f;
    for (int r = 0; r < 11; ++r) {
        __syncthreads();
        red[tid] = acc[r];
        __syncthreads();
        if (tid < 128) {
            float h = red[tid] + red[tid + 128] + b0v;
            h = h > 0.f ? h : 0.f;
            if (r == 0) {
                hcat[tid] = h;
            } else {
                int n1 = loadI(neighs1, b * K1 + (r - 1), f64);
                float hist = loadF_m(history, (long long)n1 * HIDDEN + tid, fbf);
                S += 0.5f * (h - hist);
            }
        }
    }
    if (tid < 128) {
#pragma unroll
        for (int u = 0; u < N_HIST; ++u) {
            int hn = loadI(h_nodes, b * N_HIST + u, f64);
            S += loadF_m(history, (long long)hn * HIDDEN + tid, fbf);
        }
        hcat[HIDDEN + tid] = S * (1.0f / 15.0f);
    }
    __syncthreads();

    const int n = tid & 63;
    const int seg = tid >> 6;
    float p = 0.f;
#pragma unroll 8
    for (int i = seg * 64; i < seg * 64 + 64; ++i)
        p += hcat[i] * loadF_m(W1, (long long)i * N_CLASS + n, fbf);
    red[tid] = p;
    __syncthreads();
    if (tid < 64) {
        float a = red[tid] + red[tid + 64] + red[tid + 128] + red[tid + 192]
                + loadF_m(b1, tid, fbf);
        a = a > 0.f ? a : 0.f;
        out[(long long)b * N_CLASS + tid] = a;
    }
}

// ---------------------------------------------------------------------------
extern "C" void kernel_launch(void* const* d_in, const int* in_sizes, int n_in,
                              void* d_out, int out_size, void* d_ws, size_t ws_size,
                              hipStream_t stream) {
    (void)out_size;
    const long long want[11] = {25600000, 12800000, 65536, 128, 16384, 64,
                                1024, 25600, 10240, 256000, 5120};
    const void* bp[11];
    for (int j = 0; j < 11; ++j) bp[j] = d_in[j < n_in ? j : 0];
    for (int j = 0; j < 11; ++j) {
        if (j < n_in && (long long)in_sizes[j] == want[j]) continue;
        for (int i = 0; i < n_in; ++i)
            if ((long long)in_sizes[i] == want[j]) { bp[j] = d_in[i]; break; }
    }

    // New-path ws layout: W0T2 f16 (131072 B) | P f16 (51,200,000 B) | flag
    const size_t P_BYTES = (size_t)N_NODES * 256 * 2;          // 51,200,000
    const size_t WS_NEW  = 131072 + P_BYTES + 16;
    // Old-path ws layout: W0T bf16 (131072 B) | H fp32 (5767168 B) | flag
    const size_t WS_OLD  = 131072 + 5767168 + 16;

    if (ws_size >= WS_NEW) {
        char* ws = (char*)d_ws;
        u16* W0T2 = (u16*)ws;
        u16* P    = (u16*)(ws + 131072);
        int* flag = (int*)(ws + 131072 + P_BYTES);

        k_transpose_w0h<<<dim3(16, 4), dim3(32, 8), 0, stream>>>(
            (const float*)bp[2], W0T2, bp[6], flag);
        k_proj8<<<P8_NBLK, 512, 0, stream>>>((const float*)bp[0], W0T2, P);
        k_gf<<<BATCH, 256, 0, stream>>>(
            P, (const float*)bp[1], bp[6], bp[7], bp[8], bp[9], bp[10],
            (const float*)bp[3], (const float*)bp[4], (const float*)bp[5],
            (float*)d_out, flag);
        return;
    }

    if (ws_size >= WS_OLD) {   // proven previous path
        char* ws = (char*)d_ws;
        u16* W0T  = (u16*)ws;
        float* H  = (float*)(ws + 131072);
        int* flag = (int*)(ws + 131072 + 5767168);

        k_detect<<<1, 1, 0, stream>>>(bp[6], flag);
        k_transpose_w0<<<dim3(16, 4), dim3(32, 8), 0, stream>>>((const float*)bp[2], W0T);
        k_layer0<<<M_TOTAL / 16, 512, 0, stream>>>(
            (const float*)bp[0], bp[6], bp[7], bp[8], bp[9], W0T,
            (const float*)bp[3], H, flag);
        k_final<<<BATCH, 256, 0, stream>>>(
            H, (const float*)bp[1], bp[8], bp[10],
            (const float*)bp[4], (const float*)bp[5], (float*)d_out, flag);
        return;
    }

    k_fused<<<BATCH, 256, 0, stream>>>(
        bp[0], bp[1], bp[2], bp[3], bp[4], bp[5],
        bp[6], bp[7], bp[8], bp[9], bp[10], (float*)d_out);
}

// Round 9
// 55.480 us; speedup vs baseline: 2.6139x; 2.6139x over previous
//
#include <hip/hip_runtime.h>

#define N_FEATS 256
#define HIDDEN  128
#define N_CLASS 64
#define BATCH   1024
#define K0      25
#define K1      10
#define N_HIST  5
#define M_TOTAL (BATCH + BATCH * K1)   // 11264 layer-0 rows
#define KDIM    512
#define N_NODES 100000

typedef unsigned short u16;
typedef short bf16x8 __attribute__((ext_vector_type(8)));
typedef _Float16 f16x8 __attribute__((ext_vector_type(8)));
typedef float f32x4 __attribute__((ext_vector_type(4)));

static __device__ __forceinline__ u16 f2bf(float f) {
    union { float f; unsigned int i; } v;
    v.f = f;
    unsigned int x = v.i;
    x += ((x >> 16) & 1u) + 0x7FFFu;   // round-to-nearest-even
    return (u16)(x >> 16);
}
static __device__ __forceinline__ unsigned int pack2(float lo, float hi) {
    return (unsigned int)f2bf(lo) | ((unsigned int)f2bf(hi) << 16);
}
static __device__ __forceinline__ u16 f2h(float f) {
    union { _Float16 h; u16 u; } v;
    v.h = (_Float16)f;                 // v_cvt_f16_f32, RTE
    return v.u;
}
// Dual-width int load: little-endian low word == value for both int32/int64.
static __device__ __forceinline__ int loadI(const void* p, long long i, int f64) {
    const char* cp = (const char*)p + (f64 ? (i << 3) : (i << 2));
    return *(const int*)cp;
}

// ---------------------------------------------------------------------------
// int64-vs-int32 detection (odd int32 slots of nodes all zero => int64).
// ---------------------------------------------------------------------------
__global__ void k_detect(const void* __restrict__ nodes, int* __restrict__ flag) {
    if (threadIdx.x == 0 && blockIdx.x == 0) {
        const int* p = (const int*)nodes;
        int f = 1;
        for (int i = 0; i < 8; ++i)
            if (p[2 * i + 1] != 0) f = 0;
        *flag = f;
    }
}

// ===========================================================================
// PROJECTION PATH (R3 configuration -- best measured, 55.7us):
// P = feats @ [W0_top | W0_bot] (100000 x 256, fp16), then layer-0 rows are
// pure gathers of 256B P-slices instead of 26KB of feats.
// Session conclusion (R0-R8): every structurally-sane projection schedule
// (LDS dbuf / barrier-free / drain-free / half-work split) lands at
// 55.7-58.5us total; effective BW envelope ~2.5-2.75 TB/s for ~130-155MB of
// demand, matching the harness's 400MB@7TB/s L3 poison-fill draining during
// our window. R3 is the measured optimum of that family; NT loads (R7,
// -5.6us regression) and direct-from-global MFMA layout (R8, uncoalesced,
// VGPR=64 proves B-frags sunk) are reverted.
// ===========================================================================

// W0 fp32 (512x128) -> fp16 W0T2 (256x256). Folds int64 detection.
__global__ void k_transpose_w0h(const float* __restrict__ W0, u16* __restrict__ W0T2,
                                const void* __restrict__ nodes, int* __restrict__ flag) {
    if (threadIdx.x == 0 && threadIdx.y == 0 && blockIdx.x == 0 && blockIdx.y == 0) {
        const int* p = (const int*)nodes;
        int f = 1;
        for (int i = 0; i < 8; ++i)
            if (p[2 * i + 1] != 0) f = 0;
        *flag = f;
    }
    __shared__ u16 tile[32][33];
    int tx = threadIdx.x;            // 0..31
    int ty = threadIdx.y;            // 0..7
    int k0 = blockIdx.x * 32;        // over K=512 (16 blocks)
    int n0 = blockIdx.y * 32;        // over N=128 (4 blocks)
#pragma unroll
    for (int i = 0; i < 32; i += 8)
        tile[ty + i][tx] = f2h(W0[(size_t)(k0 + ty + i) * HIDDEN + n0 + tx]);
    __syncthreads();
    int roff = (k0 >= 256) ? 128 : 0;
    int kk = k0 & 255;
#pragma unroll
    for (int i = 0; i < 32; i += 8)
        W0T2[(size_t)(n0 + ty + i + roff) * 256 + kk + tx] = tile[tx][ty + i];
}

// Projection GEMM (R3-proven): P[100000][256] fp16 = f16(feats) @ f16(W0cat).
// Persistent chunked grid: 512 blocks (2/CU), block owns 6-7 contiguous
// 32-row tiles. 8 waves x 32 output cols; B-frags register-resident.
// __launch_bounds__(512,4) pins VGPR<=128 -> 2 blocks/CU. Double-buffered
// LDS A-tiles; loads for tile t+2 issued during tile t. Output staged
// through the dead buffer and stored as coalesced dwordx4 rows.
#define TROWS      32
#define NTILES     3125               // 3125 * 32 = 100000 rows exactly
#define PROJ_NBLK  512
__global__ __launch_bounds__(512, 4) void k_proj3(
        const float* __restrict__ feats,
        const u16* __restrict__ W0T2,
        u16* __restrict__ P) {
    __shared__ u16 Xs[2][TROWS][256 + 8];   // +8 u16 pad: row stride 528B
    const int tid = threadIdx.x;
    const int wv = tid >> 6;
    const int lane = tid & 63;
    const int m = lane & 15;
    const int q = lane >> 4;
    const int base = NTILES / PROJ_NBLK;            // 6
    const int rem = NTILES - base * PROJ_NBLK;      // 53
    const int bi = blockIdx.x;
    const int s0 = bi * base + (bi < rem ? bi : rem);
    const int cnt = base + (bi < rem ? 1 : 0);      // 6 or 7 (always >= 2)

    // Loop-invariant B fragments (W0T2 rows = output cols, K contiguous).
    f16x8 B0[8], B1[8];
    {
        const u16* bb = W0T2 + (size_t)(wv * 32 + m) * 256 + q * 8;
#pragma unroll
        for (int kk = 0; kk < 8; ++kk) {
            B0[kk] = *(const f16x8*)(bb + kk * 32);
            B1[kk] = *(const f16x8*)(bb + 16 * 256 + kk * 32);
        }
    }

    // Staging: wave wv loads rows wv*4..wv*4+3 of each 32-row tile; one full
    // 1KB feat row per wave-load (64 lanes x float4).
    float4 st[4];
    const float* fbase = feats + (size_t)(wv * 4) * N_FEATS + lane * 4;

#define PROJ_ISSUE(t)                                                         \
    {                                                                         \
        const float* fp_ = fbase + (size_t)(t) * (TROWS * N_FEATS);           \
        _Pragma("unroll")                                                     \
        for (int i = 0; i < 4; ++i)                                           \
            st[i] = *(const float4*)(fp_ + (size_t)i * N_FEATS);              \
    }
#define PROJ_WRITE(b)                                                         \
    {                                                                         \
        _Pragma("unroll")                                                     \
        for (int i = 0; i < 4; ++i) {                                         \
            ushort4 pk;                                                       \
            pk.x = f2h(st[i].x); pk.y = f2h(st[i].y);                         \
            pk.z = f2h(st[i].z); pk.w = f2h(st[i].w);                         \
            *(ushort4*)&Xs[b][wv * 4 + i][lane * 4] = pk;                     \
        }                                                                     \
    }

    PROJ_ISSUE(s0);
    PROJ_WRITE(0);
    PROJ_ISSUE(s0 + 1);               // cnt >= 2 always, no OOB
    __syncthreads();

    int cur = 0;
    for (int tt = 0; tt < cnt; ++tt) {
        const int t = s0 + tt;
        f32x4 a00 = (f32x4){0.f,0.f,0.f,0.f}, a01 = (f32x4){0.f,0.f,0.f,0.f};
        f32x4 a10 = (f32x4){0.f,0.f,0.f,0.f}, a11 = (f32x4){0.f,0.f,0.f,0.f};
#pragma unroll
        for (int kk = 0; kk < 8; ++kk) {
            f16x8 f0 = *(const f16x8*)&Xs[cur][m][kk * 32 + q * 8];
            f16x8 f1 = *(const f16x8*)&Xs[cur][m + 16][kk * 32 + q * 8];
            a00 = __builtin_amdgcn_mfma_f32_16x16x32_f16(f0, B0[kk], a00, 0, 0, 0);
            a01 = __builtin_amdgcn_mfma_f32_16x16x32_f16(f0, B1[kk], a01, 0, 0, 0);
            a10 = __builtin_amdgcn_mfma_f32_16x16x32_f16(f1, B0[kk], a10, 0, 0, 0);
            a11 = __builtin_amdgcn_mfma_f32_16x16x32_f16(f1, B1[kk], a11, 0, 0, 0);
        }
        __syncthreads();               // all waves done reading Xs[cur]
        // Output tile -> dead buffer Xs[cur].  D: row=q*4+r, col=lane&15.
#pragma unroll
        for (int r = 0; r < 4; ++r) {
            Xs[cur][q * 4 + r][wv * 32 + m]           = f2h(a00[r]);
            Xs[cur][q * 4 + r][wv * 32 + 16 + m]      = f2h(a01[r]);
            Xs[cur][16 + q * 4 + r][wv * 32 + m]      = f2h(a10[r]);
            Xs[cur][16 + q * 4 + r][wv * 32 + 16 + m] = f2h(a11[r]);
        }
        // Stage next tile's feats into the other buffer; issue loads for t+2.
        if (tt + 1 < cnt) {
            PROJ_WRITE(cur ^ 1);
            if (tt + 2 < cnt) PROJ_ISSUE(t + 2);
        }
        __syncthreads();               // out-tile + next A-tile both visible
        // Coalesced store: 512 threads x 2 x 16B cover the 32x256 fp16 tile.
        {
            const int row0 = tid >> 5;             // 0..15
            const int c8 = (tid & 31) * 8;         // fp16 column
#pragma unroll
            for (int p = 0; p < 2; ++p) {
                uint4 w = *(const uint4*)&Xs[cur][row0 + p * 16][c8];
                *(uint4*)(P + (size_t)(t * TROWS + row0 + p * 16) * 256 + c8) = w;
            }
        }
        cur ^= 1;
    }
#undef PROJ_ISSUE
#undef PROJ_WRITE
}

// Fused gather + layer-1 (R3-proven): one 256-thread block (4 waves) per
// batch row b. Stage A: 11 layer-0 rows as relu(P_top[self] +
// mean_k P_bot[idx_k] + b0); Stage B/C: identical math to proven k_final.
__global__ __launch_bounds__(256) void k_gf(
        const u16* __restrict__ P,
        const float* __restrict__ history,
        const void* __restrict__ nodes,
        const void* __restrict__ neighs0,
        const void* __restrict__ neighs1,
        const void* __restrict__ neighs0_nb,
        const void* __restrict__ h_nodes,
        const float* __restrict__ b0,
        const float* __restrict__ W1,
        const float* __restrict__ b1,
        float* __restrict__ out,
        const int* __restrict__ flag) {
    __shared__ float Hs[11][128];
    __shared__ float hcat[2 * HIDDEN];
    __shared__ float red[256];
    const int f64 = *flag;
    const int tid = threadIdx.x;
    const int b = blockIdx.x;
    const int wv = tid >> 6;
    const int lane = tid & 63;
    const int m = lane & 15;
    const int grp = lane >> 4;

    // ---- Stage A: rows wv, wv+4, wv+8 (<11)
    for (int r = wv; r < 11; r += 4) {
        int selfIdx;
        const void* nbp;
        long long nbo;
        if (r == 0) {
            selfIdx = loadI(nodes, b, f64);
            nbp = neighs0; nbo = (long long)b * K0;
        } else {
            int rr = b * K1 + (r - 1);
            selfIdx = loadI(neighs1, rr, f64);
            nbp = neighs0_nb; nbo = (long long)rr * K0;
        }
        int idx[K0];
#pragma unroll
        for (int k = 0; k < K0; ++k) idx[k] = loadI(nbp, nbo + k, f64);

        float a[8];
#pragma unroll
        for (int i = 0; i < 8; ++i) a[i] = 0.f;
#pragma unroll
        for (int k = 0; k < 7; ++k) {
            int k1 = 4 * k + grp;
            if (k1 < K0) {
                f16x8 v = *(const f16x8*)(P + (size_t)idx[k1] * 256 + 128 + m * 8);
#pragma unroll
                for (int i = 0; i < 8; ++i) a[i] += (float)v[i];
            }
        }
#pragma unroll
        for (int i = 0; i < 8; ++i) {
            a[i] += __shfl_xor(a[i], 16);
            a[i] += __shfl_xor(a[i], 32);
        }
        if (grp == 0) {
            f16x8 sv = *(const f16x8*)(P + (size_t)selfIdx * 256 + m * 8);
            const float inv = 1.0f / (float)K0;
#pragma unroll
            for (int i = 0; i < 8; ++i) {
                float y = a[i] * inv + (float)sv[i] + b0[m * 8 + i];
                Hs[r][m * 8 + i] = y > 0.f ? y : 0.f;
            }
        }
    }
    __syncthreads();

    // ---- Stage B: half 0 does t=0..4 (+h1), half 1 does t=5..9 (+history).
    const int j = tid & 127;
    const int half = tid >> 7;
    float S = 0.f;
    if (half == 0) hcat[j] = Hs[0][j];
#pragma unroll
    for (int t = half * 5; t < half * 5 + 5; ++t) {
        int n1 = loadI(neighs1, b * K1 + t, f64);
        S += 0.5f * (Hs[1 + t][j] - history[(size_t)n1 * HIDDEN + j]);
    }
    if (half == 1) {
#pragma unroll
        for (int u = 0; u < N_HIST; ++u) {
            int hn = loadI(h_nodes, b * N_HIST + u, f64);
            S += history[(size_t)hn * HIDDEN + j];
        }
    }
    red[tid] = S;
    __syncthreads();
    if (half == 0)
        hcat[HIDDEN + j] = (red[j] + red[HIDDEN + j]) * (1.0f / 15.0f);
    __syncthreads();

    // ---- Stage C: 4 threads per class column, 64-length partial dots.
    const int n = tid & 63;
    const int seg = tid >> 6;
    float p = 0.f;
#pragma unroll 8
    for (int i = seg * 64; i < seg * 64 + 64; ++i)
        p += hcat[i] * W1[(size_t)i * N_CLASS + n];
    red[tid] = p;
    __syncthreads();
    if (tid < 64) {
        float a = red[tid] + red[tid + 64] + red[tid + 128] + red[tid + 192]
                + b1[tid];
        a = a > 0.f ? a : 0.f;
        out[(size_t)b * N_CLASS + tid] = a;
    }
}

// ===========================================================================
// MIDDLE TIER (proven 65.5us path): kept verbatim for ws too small for P.
// ===========================================================================
__global__ void k_transpose_w0(const float* __restrict__ W0, u16* __restrict__ W0T) {
    __shared__ u16 tile[32][33];
    int tx = threadIdx.x;
    int ty = threadIdx.y;
    int k0 = blockIdx.x * 32;
    int n0 = blockIdx.y * 32;
#pragma unroll
    for (int i = 0; i < 32; i += 8)
        tile[ty + i][tx] = f2bf(W0[(size_t)(k0 + ty + i) * HIDDEN + n0 + tx]);
    __syncthreads();
#pragma unroll
    for (int i = 0; i < 32; i += 8)
        W0T[(size_t)(n0 + ty + i) * KDIM + k0 + tx] = tile[tx][ty + i];
}

__global__ __launch_bounds__(512) void k_layer0(
        const float* __restrict__ feats,
        const void* __restrict__ nodes,
        const void* __restrict__ neighs0,
        const void* __restrict__ neighs1,
        const void* __restrict__ neighs0_nb,
        const u16* __restrict__ W0T,
        const float* __restrict__ b0,
        float* __restrict__ H,
        const int* __restrict__ flag) {
    __shared__ u16 Xs[16][KDIM + 8];
    const int f64 = *flag;
    int wv = threadIdx.x >> 6;
    int lane = threadIdx.x & 63;
    int row0 = blockIdx.x * 16;
    int d = lane * 4;

#pragma unroll
    for (int i = 0; i < 2; ++i) {
        int lr = wv * 2 + i;
        int g = row0 + lr;
        int selfIdx;
        const void* nbp;
        long long nbo;
        if (g < BATCH) {
            selfIdx = loadI(nodes, g, f64);
            nbp = neighs0; nbo = (long long)g * K0;
        } else {
            int rr = g - BATCH;
            selfIdx = loadI(neighs1, rr, f64);
            nbp = neighs0_nb; nbo = (long long)rr * K0;
        }
        int idx[K0];
#pragma unroll
        for (int k = 0; k < K0; ++k) idx[k] = loadI(nbp, nbo + k, f64);

        float4 sv = *(const float4*)(feats + (size_t)selfIdx * N_FEATS + d);
        float a0 = 0.f, a1 = 0.f, a2 = 0.f, a3 = 0.f;
#pragma unroll
        for (int k = 0; k < K0; ++k) {
            float4 v = *(const float4*)(feats + (size_t)idx[k] * N_FEATS + d);
            a0 += v.x; a1 += v.y; a2 += v.z; a3 += v.w;
        }
        const float inv = 1.0f / (float)K0;
        uint2 spk, mpk;
        spk.x = pack2(sv.x, sv.y);
        spk.y = pack2(sv.z, sv.w);
        mpk.x = pack2(a0 * inv, a1 * inv);
        mpk.y = pack2(a2 * inv, a3 * inv);
        *(uint2*)&Xs[lr][d] = spk;
        *(uint2*)&Xs[lr][N_FEATS + d] = mpk;
    }
    __syncthreads();

    int m = lane & 15;
    int q = lane >> 4;
    f32x4 acc = (f32x4){0.f, 0.f, 0.f, 0.f};
    const u16* bbase = W0T + (size_t)(wv * 16 + m) * KDIM + q * 8;
#pragma unroll
    for (int k0 = 0; k0 < KDIM; k0 += 32) {
        bf16x8 af = *(const bf16x8*)&Xs[m][k0 + q * 8];
        bf16x8 bf = *(const bf16x8*)(bbase + k0);
        acc = __builtin_amdgcn_mfma_f32_16x16x32_bf16(af, bf, acc, 0, 0, 0);
    }
    int col = wv * 16 + m;
    float bias = b0[col];
#pragma unroll
    for (int r = 0; r < 4; ++r) {
        float y = acc[r] + bias;
        y = y > 0.f ? y : 0.f;
        H[(size_t)(row0 + q * 4 + r) * HIDDEN + col] = y;
    }
}

__global__ __launch_bounds__(256) void k_final(
        const float* __restrict__ H,
        const float* __restrict__ history,
        const void* __restrict__ neighs1,
        const void* __restrict__ h_nodes,
        const float* __restrict__ W1,
        const float* __restrict__ b1,
        float* __restrict__ out,
        const int* __restrict__ flag) {
    __shared__ float hcat[2 * HIDDEN];
    __shared__ float red[256];
    const int f64 = *flag;
    const int tid = threadIdx.x;
    const int b = blockIdx.x;
    const int j = tid & 127;
    const int half = tid >> 7;

    float S = 0.f;
    if (half == 0) hcat[j] = H[(size_t)b * HIDDEN + j];
#pragma unroll
    for (int t = half * 5; t < half * 5 + 5; ++t) {
        float orig = H[(size_t)(BATCH + b * K1 + t) * HIDDEN + j];
        int n1 = loadI(neighs1, b * K1 + t, f64);
        float hist = history[(size_t)n1 * HIDDEN + j];
        S += 0.5f * (orig - hist);
    }
    if (half == 1) {
#pragma unroll
        for (int u = 0; u < N_HIST; ++u) {
            int hn = loadI(h_nodes, b * N_HIST + u, f64);
            S += history[(size_t)hn * HIDDEN + j];
        }
    }
    red[tid] = S;
    __syncthreads();
    if (half == 0)
        hcat[HIDDEN + j] = (red[j] + red[HIDDEN + j]) * (1.0f / 15.0f);
    __syncthreads();

    const int n = tid & 63;
    const int seg = tid >> 6;
    float p = 0.f;
#pragma unroll 8
    for (int i = seg * 64; i < seg * 64 + 64; ++i)
        p += hcat[i] * W1[(size_t)i * N_CLASS + n];
    red[tid] = p;
    __syncthreads();
    if (tid < 64) {
        float a = red[tid] + red[tid + 64] + red[tid + 128] + red[tid + 192]
                + b1[tid];
        a = a > 0.f ? a : 0.f;
        out[(size_t)b * N_CLASS + tid] = a;
    }
}

// ===========================================================================
// Fallback: known-good monolithic kernel (used only if ws too small).
// ===========================================================================
static __device__ __forceinline__ float loadF_m(const void* p, long long i, int fbf) {
    const char* cp = (const char*)p + (fbf ? (i << 1) : (i << 2));
    if (fbf) {
        union { unsigned int u; float f; } v;
        v.u = ((unsigned int)(*(const u16*)cp)) << 16;
        return v.f;
    }
    return *(const float*)cp;
}

__global__ __launch_bounds__(256) void k_fused(
        const void* __restrict__ feats,
        const void* __restrict__ history,
        const void* __restrict__ W0,
        const void* __restrict__ b0,
        const void* __restrict__ W1,
        const void* __restrict__ b1,
        const void* __restrict__ nodes,
        const void* __restrict__ neighs0,
        const void* __restrict__ neighs1,
        const void* __restrict__ neighs0_nb,
        const void* __restrict__ h_nodes,
        float* __restrict__ out) {
    __shared__ float W0s[32][128];
    __shared__ float Xs[11][KDIM];
    __shared__ float hcat[2 * HIDDEN];
    __shared__ float red[256];
    __shared__ int ibuf[K0 + 1];
    __shared__ int sflags[2];

    const int tid = threadIdx.x;
    const int b = blockIdx.x;

    if (tid == 0) {
        const int* ip = (const int*)nodes;
        int f = 1;
        for (int i = 0; i < 8; ++i)
            if (ip[2 * i + 1] != 0) f = 0;
        sflags[0] = f;
        const u16* qp = (const u16*)feats;
        int cnt = 0;
        for (int i = 0; i < 64; ++i) {
            int e = (qp[2 * i] >> 7) & 0xFF;
            if (e >= 90 && e <= 134) cnt++;
        }
        sflags[1] = (cnt >= 40) ? 1 : 0;
    }
    __syncthreads();
    const int f64 = sflags[0];
    const int fbf = sflags[1];

    for (int r = 0; r < 11; ++r) {
        __syncthreads();
        if (tid < K0) {
            long long nbo = (r == 0) ? ((long long)b * K0)
                                     : ((long long)(b * K1 + (r - 1)) * K0);
            const void* nbp = (r == 0) ? neighs0 : neighs0_nb;
            ibuf[tid] = loadI(nbp, nbo + tid, f64);
        } else if (tid == K0) {
            ibuf[K0] = (r == 0) ? loadI(nodes, b, f64)
                                : loadI(neighs1, b * K1 + (r - 1), f64);
        }
        __syncthreads();
        int sidx = ibuf[K0];
        Xs[r][tid] = loadF_m(feats, (long long)sidx * N_FEATS + tid, fbf);
        float s = 0.f;
#pragma unroll
        for (int k = 0; k < K0; ++k)
            s += loadF_m(feats, (long long)ibuf[k] * N_FEATS + tid, fbf);
        Xs[r][N_FEATS + tid] = s * (1.0f / (float)K0);
    }
    __syncthreads();

    const int c = tid & 127;
    const int ph = tid >> 7;
    float acc[11];
#pragma unroll
    for (int r = 0; r < 11; ++r) acc[r] = 0.f;

    for (int s = 0; s < 16; ++s) {
        __syncthreads();
#pragma unroll
        for (int i = 0; i < 16; ++i) {
            int idx = tid + 256 * i;
            int k = idx >> 7, cc = idx & 127;
            W0s[k][cc] = loadF_m(W0, (long long)(32 * s + k) * HIDDEN + cc, fbf);
        }
        __syncthreads();
        const int kb = 32 * s + 16 * ph;
#pragma unroll
        for (int r = 0; r < 11; ++r) {
            float a = 0.f;
#pragma unroll
            for (int j = 0; j < 16; ++j)
                a += Xs[r][kb + j] * W0s[16 * ph + j][c];
            acc[r] += a;
        }
    }

    float S = 0.f;
    float b0v = (tid < 128) ? loadF_m(b0, tid, fbf) : 0.f;
    for (int r = 0; r < 11; ++r) {
        __syncthreads();
        red[tid] = acc[r];
        __syncthreads();
        if (tid < 128) {
            float h = red[tid] + red[tid + 128] + b0v;
            h = h > 0.f ? h : 0.f;
            if (r == 0) {
                hcat[tid] = h;
            } else {
                int n1 = loadI(neighs1, b * K1 + (r - 1), f64);
                float hist = loadF_m(history, (long long)n1 * HIDDEN + tid, fbf);
                S += 0.5f * (h - hist);
            }
        }
    }
    if (tid < 128) {
#pragma unroll
        for (int u = 0; u < N_HIST; ++u) {
            int hn = loadI(h_nodes, b * N_HIST + u, f64);
            S += loadF_m(history, (long long)hn * HIDDEN + tid, fbf);
        }
        hcat[HIDDEN + tid] = S * (1.0f / 15.0f);
    }
    __syncthreads();

    const int n = tid & 63;
    const int seg = tid >> 6;
    float p = 0.f;
#pragma unroll 8
    for (int i = seg * 64; i < seg * 64 + 64; ++i)
        p += hcat[i] * loadF_m(W1, (long long)i * N_CLASS + n, fbf);
    red[tid] = p;
    __syncthreads();
    if (tid < 64) {
        float a = red[tid] + red[tid + 64] + red[tid + 128] + red[tid + 192]
                + loadF_m(b1, tid, fbf);
        a = a > 0.f ? a : 0.f;
        out[(long long)b * N_CLASS + tid] = a;
    }
}

// ---------------------------------------------------------------------------
extern "C" void kernel_launch(void* const* d_in, const int* in_sizes, int n_in,
                              void* d_out, int out_size, void* d_ws, size_t ws_size,
                              hipStream_t stream) {
    (void)out_size;
    const long long want[11] = {25600000, 12800000, 65536, 128, 16384, 64,
                                1024, 25600, 10240, 256000, 5120};
    const void* bp[11];
    for (int j = 0; j < 11; ++j) bp[j] = d_in[j < n_in ? j : 0];
    for (int j = 0; j < 11; ++j) {
        if (j < n_in && (long long)in_sizes[j] == want[j]) continue;
        for (int i = 0; i < n_in; ++i)
            if ((long long)in_sizes[i] == want[j]) { bp[j] = d_in[i]; break; }
    }

    // New-path ws layout: W0T2 f16 (131072 B) | P f16 (51,200,000 B) | flag
    const size_t P_BYTES = (size_t)N_NODES * 256 * 2;          // 51,200,000
    const size_t WS_NEW  = 131072 + P_BYTES + 16;
    // Old-path ws layout: W0T bf16 (131072 B) | H fp32 (5767168 B) | flag
    const size_t WS_OLD  = 131072 + 5767168 + 16;

    if (ws_size >= WS_NEW) {
        char* ws = (char*)d_ws;
        u16* W0T2 = (u16*)ws;
        u16* P    = (u16*)(ws + 131072);
        int* flag = (int*)(ws + 131072 + P_BYTES);

        k_transpose_w0h<<<dim3(16, 4), dim3(32, 8), 0, stream>>>(
            (const float*)bp[2], W0T2, bp[6], flag);
        k_proj3<<<PROJ_NBLK, 512, 0, stream>>>((const float*)bp[0], W0T2, P);
        k_gf<<<BATCH, 256, 0, stream>>>(
            P, (const float*)bp[1], bp[6], bp[7], bp[8], bp[9], bp[10],
            (const float*)bp[3], (const float*)bp[4], (const float*)bp[5],
            (float*)d_out, flag);
        return;
    }

    if (ws_size >= WS_OLD) {   // proven previous path
        char* ws = (char*)d_ws;
        u16* W0T  = (u16*)ws;
        float* H  = (float*)(ws + 131072);
        int* flag = (int*)(ws + 131072 + 5767168);

        k_detect<<<1, 1, 0, stream>>>(bp[6], flag);
        k_transpose_w0<<<dim3(16, 4), dim3(32, 8), 0, stream>>>((const float*)bp[2], W0T);
        k_layer0<<<M_TOTAL / 16, 512, 0, stream>>>(
            (const float*)bp[0], bp[6], bp[7], bp[8], bp[9], W0T,
            (const float*)bp[3], H, flag);
        k_final<<<BATCH, 256, 0, stream>>>(
            H, (const float*)bp[1], bp[8], bp[10],
            (const float*)bp[4], (const float*)bp[5], (float*)d_out, flag);
        return;
    }

    k_fused<<<BATCH, 256, 0, stream>>>(
        bp[0], bp[1], bp[2], bp[3], bp[4], bp[5],
        bp[6], bp[7], bp[8], bp[9], bp[10], (float*)d_out);
}